// Round 1
// baseline (380.798 us; speedup 1.0000x reference)
//
#include <hip/hip_runtime.h>

#define PI_F 3.14159265358979323846f

__device__ __forceinline__ float2 cmulf(float2 a, float c, float s) {
    return make_float2(a.x * c - a.y * s, a.x * s + a.y * c);
}

// One workgroup = one row of length 4096.
// Computes IDCT (IDXST=false) or IDXST (IDXST=true) of the row via the
// Makhoul half-spectrum trick + a 2048-point complex unnormalized IFFT
// (Stockham, radix-4 x5 + radix-2 x1) in LDS.
template<bool IDXST>
__global__ __launch_bounds__(256)
void row_fft_kernel(const float* in, float* out, const float2* expk)
{
    __shared__ float smem[8192];              // 32 KB
    float*  xs = smem;                        // [0, 4096) staging (real row)
    float2* za = (float2*)(smem + 4096);      // 2048 complex
    float2* zb = (float2*)smem;               // overlays xs (xs dead by then)

    const int t = threadIdx.x;
    const size_t row = blockIdx.x;
    const float* src = in  + row * 4096;
    float*       dst = out + row * 4096;

    // ---- load row, coalesced float4 ----
    {
        const float4* s4 = (const float4*)src;
        float4* x4 = (float4*)xs;
        #pragma unroll
        for (int i = 0; i < 4; i++) x4[t + 256 * i] = s4[t + 256 * i];
    }
    __syncthreads();

    // ---- build Z_k = A_k + i*B_k (k = 0..2047) ----
    // V_k = 0.5*(X_k - i*Xr_k)*e_k,  e_k = expk[k] = exp(i*pi*k/8192)
    // A_k = V_k + V_{k+2048};  B_k = (V_k - V_{k+2048}) * exp(i*pi*k/2048)
    // For IDXST the input is X'_k = X_{(4096-k)%4096}, X'_0 = 0.
    #pragma unroll
    for (int i = 0; i < 8; i++) {
        int k = t + 256 * i;                  // 0..2047
        float Xa, Xra, Xb, Xrb;
        if (IDXST) {
            Xa  = (k == 0) ? 0.0f : xs[4096 - k];
            Xra = (k == 0) ? 0.0f : xs[k];
            Xb  = xs[2048 - k];               // X'_{k+2048}
            Xrb = xs[k + 2048];               // Xr'_{k+2048}
        } else {
            Xa  = xs[k];
            Xra = (k == 0) ? 0.0f : xs[4096 - k];
            Xb  = xs[k + 2048];
            Xrb = xs[2048 - k];
        }
        float2 ea = expk[k];
        float2 eb = expk[k + 2048];
        float Var = 0.5f * (Xa * ea.x + Xra * ea.y);
        float Vai = 0.5f * (Xa * ea.y - Xra * ea.x);
        float Vbr = 0.5f * (Xb * eb.x + Xrb * eb.y);
        float Vbi = 0.5f * (Xb * eb.y - Xrb * eb.x);
        float Ar = Var + Vbr, Ai = Vai + Vbi;
        float Dr = Var - Vbr, Di = Vai - Vbi;
        float cw, sw;
        __sincosf(PI_F * (float)k * (1.0f / 2048.0f), &sw, &cw);
        float Br = Dr * cw - Di * sw;
        float Bi = Dr * sw + Di * cw;
        za[k] = make_float2(Ar - Bi, Ai + Br);   // A + i*B
    }
    __syncthreads();

    // ---- 2048-pt complex IFFT (sign = +1, unnormalized), Stockham ----
    float2* sb = za;
    float2* db = zb;
    int Ns = 1;
    #pragma unroll
    for (int s = 0; s < 5; s++) {             // radix-4 stages, Ns = 1,4,16,64,256
        int ls = 2 * s;                       // log2(Ns)
        #pragma unroll
        for (int ii = 0; ii < 2; ii++) {
            int j = t + 256 * ii;             // 0..511
            float2 v0 = sb[j];
            float2 v1 = sb[j + 512];
            float2 v2 = sb[j + 1024];
            float2 v3 = sb[j + 1536];
            int jm = j & (Ns - 1);
            float ang = (0.5f * PI_F) * (float)jm / (float)Ns;  // 2*pi*jm/(4*Ns)
            float s1, c1;
            __sincosf(ang, &s1, &c1);
            float c2 = c1 * c1 - s1 * s1, s2 = 2.0f * c1 * s1;
            float c3 = c1 * c2 - s1 * s2, s3 = c1 * s2 + s1 * c2;
            v1 = cmulf(v1, c1, s1);
            v2 = cmulf(v2, c2, s2);
            v3 = cmulf(v3, c3, s3);
            float2 a0 = make_float2(v0.x + v2.x, v0.y + v2.y);
            float2 a1 = make_float2(v0.x - v2.x, v0.y - v2.y);
            float2 a2 = make_float2(v1.x + v3.x, v1.y + v3.y);
            float2 a3 = make_float2(v1.x - v3.x, v1.y - v3.y);
            int idxD = ((j >> ls) << (ls + 2)) | jm;
            db[idxD]          = make_float2(a0.x + a2.x, a0.y + a2.y);
            db[idxD + Ns]     = make_float2(a1.x - a3.y, a1.y + a3.x);  // a1 + i*a3
            db[idxD + 2 * Ns] = make_float2(a0.x - a2.x, a0.y - a2.y);
            db[idxD + 3 * Ns] = make_float2(a1.x + a3.y, a1.y - a3.x);  // a1 - i*a3
        }
        __syncthreads();
        float2* tmp = sb; sb = db; db = tmp;
        Ns <<= 2;
    }
    // final radix-2 stage: Ns = 1024
    #pragma unroll
    for (int ii = 0; ii < 4; ii++) {
        int j = t + 256 * ii;                 // 0..1023
        float2 v0 = sb[j];
        float2 v1 = sb[j + 1024];
        float s1, c1;
        __sincosf(PI_F * (float)j * (1.0f / 1024.0f), &s1, &c1);
        v1 = cmulf(v1, c1, s1);
        db[j]        = make_float2(v0.x + v1.x, v0.y + v1.y);
        db[j + 1024] = make_float2(v0.x - v1.x, v0.y - v1.y);
    }
    __syncthreads();
    const float2* zf = db;

    // ---- de-interleave + store (float4 coalesced) ----
    // y_{4p} = Re z_p ; y_{4p+1} = Im z_{2047-p} ; y_{4p+2} = Im z_p ; y_{4p+3} = Re z_{2047-p}
    float4* d4 = (float4*)dst;
    #pragma unroll
    for (int i = 0; i < 4; i++) {
        int p = t + 256 * i;                  // 0..1023
        float2 zp = zf[p];
        float2 zq = zf[2047 - p];
        float4 o;
        if (IDXST) {
            o.x = zp.x; o.y = -zq.y; o.z = zp.y; o.w = -zq.x;
        } else {
            o.x = zp.x; o.y =  zq.y; o.z = zp.y; o.w =  zq.x;
        }
        d4[p] = o;
    }
}

// In-place per-batch square transpose (n x n, n % 64 == 0), 64x64 tile pairs.
__global__ __launch_bounds__(256)
void transpose_inplace(float* d, int n)
{
    __shared__ float ta[64][65];
    __shared__ float tb[64][65];
    int ti = blockIdx.x, tj = blockIdx.y, b = blockIdx.z;
    if (tj < ti) return;
    float* base = d + (size_t)b * n * n;
    int x  = threadIdx.x;                     // 0..63
    int y0 = threadIdx.y;                     // 0..3
    size_t offA = (size_t)(ti * 64) * n + tj * 64;
    size_t offB = (size_t)(tj * 64) * n + ti * 64;

    #pragma unroll
    for (int r = y0; r < 64; r += 4) ta[r][x] = base[offA + (size_t)r * n + x];
    if (ti != tj) {
        #pragma unroll
        for (int r = y0; r < 64; r += 4) tb[r][x] = base[offB + (size_t)r * n + x];
    }
    __syncthreads();
    if (ti != tj) {
        #pragma unroll
        for (int r = y0; r < 64; r += 4) {
            base[offA + (size_t)r * n + x] = tb[x][r];
            base[offB + (size_t)r * n + x] = ta[x][r];
        }
    } else {
        #pragma unroll
        for (int r = y0; r < 64; r += 4) base[offA + (size_t)r * n + x] = ta[x][r];
    }
}

extern "C" void kernel_launch(void* const* d_in, const int* in_sizes, int n_in,
                              void* d_out, int out_size, void* d_ws, size_t ws_size,
                              hipStream_t stream)
{
    const float*  x     = (const float*)d_in[0];
    const float2* expkM = (const float2*)d_in[1];   // (4096, 2) fp32
    const float2* expkN = (const float2*)d_in[2];   // (4096, 2) fp32
    float* out = (float*)d_out;

    const int B = in_sizes[0] / (4096 * 4096);      // = 2
    const int rows = B * 4096;

    // IDXST along N (contiguous rows of x) -> out.  (Transforms on M and N commute.)
    row_fft_kernel<true><<<rows, 256, 0, stream>>>(x, out, expkN);
    // out: (B, M, N) -> (B, N, M)
    transpose_inplace<<<dim3(64, 64, B), dim3(64, 4), 0, stream>>>(out, 4096);
    // IDCT along M (now-contiguous rows), in place.
    row_fft_kernel<false><<<rows, 256, 0, stream>>>(out, out, expkM);
    // back to (B, M, N)
    transpose_inplace<<<dim3(64, 64, B), dim3(64, 4), 0, stream>>>(out, 4096);
}